// Round 4
// baseline (656.767 us; speedup 1.0000x reference)
//
#include <hip/hip_runtime.h>
#include <stdint.h>
#include <stddef.h>

// Problem constants (fixed by the reference)
#define N_TOT  8192   // rows of adj / rows of x
#define D_FEAT 256    // feature dim
// Main-kernel tile config
#define BM 16         // rows per block (512 blocks -> 2 blocks/CU)
#define BK 64         // k per iteration
#define K_ITERS (N_TOT / BK)   // 128

typedef float f32x4_t __attribute__((ext_vector_type(4)));
typedef short s16x8_t __attribute__((ext_vector_type(8)));
typedef short s16x4_t __attribute__((ext_vector_type(4)));

// fp32 -> bf16 round-to-nearest-even (inputs finite)
__device__ __forceinline__ unsigned short f2bf(float f) {
    union { float f; unsigned int u; } a;
    a.f = f;
    unsigned int r = a.u + 0x7FFFu + ((a.u >> 16) & 1u);
    return (unsigned short)(r >> 16);
}

// streamed (read-once) load of adj: nontemporal so it doesn't evict L2-resident xT
__device__ __forceinline__ f32x4_t ld4_nt(const float* p) {
    return __builtin_nontemporal_load((const f32x4_t*)p);
}

// ---------------------------------------------------------------------------
// Pre-kernel: xT[n][k] = bf16(x[k][n]).  x: [8192][256] fp32 -> xT: [256][8192] bf16
// ---------------------------------------------------------------------------
__global__ __launch_bounds__(256) void xpose_kernel(
    const float* __restrict__ x, unsigned short* __restrict__ xT)
{
    __shared__ unsigned short T[64 * 72];   // [n][k] tile, stride 72 -> 16B-aligned rows
    const int t  = threadIdx.x;
    const int k0 = blockIdx.x * 64;
    const int n0 = blockIdx.y * 64;

    #pragma unroll
    for (int i = 0; i < 4; ++i) {
        const int kr = (t >> 4) + 16 * i;
        const int c4 = (t & 15) * 4;
        float4 v = *(const float4*)(x + (size_t)(k0 + kr) * D_FEAT + n0 + c4);
        T[(c4 + 0) * 72 + kr] = f2bf(v.x);
        T[(c4 + 1) * 72 + kr] = f2bf(v.y);
        T[(c4 + 2) * 72 + kr] = f2bf(v.z);
        T[(c4 + 3) * 72 + kr] = f2bf(v.w);
    }
    __syncthreads();
    #pragma unroll
    for (int i = 0; i < 2; ++i) {
        const int n  = (t >> 3) + 32 * i;
        const int c8 = (t & 7) * 8;
        uint4 w = *(const uint4*)&T[n * 72 + c8];
        *(uint4*)(xT + (size_t)(n0 + n) * N_TOT + k0 + c8) = w;
    }
}

// ---------------------------------------------------------------------------
// Main kernel (FUSED g, 2 blocks/CU): out[m, g*256+n] = sum_k adj_g[m,k]*x[k,n]
// Grid: 512 blocks (2/CU, 16 waves/CU -> two phase-shifted barrier groups)
// x 512 thr (8 waves). Wave w owns n-cols [32w,32w+32) of BOTH g-halves
// (B fragments shared across g).
//
// LDS: granule-major, XOR-swizzled. Granule(g,ks,fq,FL) = 16 B = 8 bf16 =
// A_g[FL][32*ks+8*fq .. +8], slot = ((g*2+ks)*4+fq)*16 + (FL ^ (4*ks+fq)).
// Staging: all 512 threads, half-granule each (float4 load -> ds_write_b64):
//   u=t>>1, hg=t&1, row=u>>4, g=(u>>3)&1, c8=u&7 (ks=c8>>2, fq=c8&3).
// Both ds_write_b64 and af ds_read_b128 are uniform 8-deep (conflict-free).
//
// Pipeline: one raw s_barrier + lgkmcnt(0) per K-step (no vmcnt drain);
// A register-prefetched 2 deep (tile it+3 issued at iter it), B 1 deep.
// ---------------------------------------------------------------------------
__global__ __launch_bounds__(512, 4) void h2gcn_kernel(
    const float* __restrict__ adj0,
    const float* __restrict__ adj1,
    const unsigned short* __restrict__ xT,
    float* __restrict__ out)
{
    const int m0   = blockIdx.x * BM;
    const int t    = threadIdx.x;
    const int lane = t & 63;
    const int w    = t >> 6;      // wave 0..7
    const int fl   = lane & 15;   // fragment row/col
    const int fq   = lane >> 4;   // fragment quad

    __shared__ __align__(16) unsigned short Asm[2][256 * 8];  // 2 x 4 KiB

    // ---- staging map: thread -> half-granule (8B) of the 2-matrix A tile
    const int u   = t >> 1;            // granule 0..255
    const int hg  = t & 1;             // half (4 floats / 4 bf16)
    const int sr  = u >> 4;            // row 0..15
    const int sg  = (u >> 3) & 1;      // which adj
    const int c8  = u & 7;             // granule col: ks=c8>>2, fq=c8&3
    const int wslot = ((sg * 2 + (c8 >> 2)) * 4 + (c8 & 3)) * 16 + (sr ^ c8);
    const int woff  = wslot * 8 + hg * 4;     // ushort offset of the 8B half
    const float* aBase = (sg ? adj1 : adj0)
                       + (size_t)(m0 + sr) * N_TOT + c8 * 8 + hg * 4;

    // ---- B fragment addresses: xT row n = 32w + 16nt + fl, k-offset 8fq
    const unsigned short* bBase0 = xT + (size_t)(32 * w + fl) * N_TOT + 8 * fq;
    const unsigned short* bBase1 = bBase0 + (size_t)16 * N_TOT;

    f32x4_t aR[2];          // A prefetch ring: slot (T+1)&1 holds tile T
    s16x8_t bR[2][2][2];    // [slot][nt][ks], slot it&1 holds B tile it
    f32x4_t acc[2][2];      // [g][nt]

    #pragma unroll
    for (int g = 0; g < 2; ++g)
        #pragma unroll
        for (int nt = 0; nt < 2; ++nt) {
            f32x4_t z = {0.0f, 0.0f, 0.0f, 0.0f};
            acc[g][nt] = z;
        }

    // ---- prologue: issue A tiles 0,1,2 and B tile 0; stage tile 0 ----
    f32x4_t a0 = ld4_nt(aBase);             // tile 0
    aR[1]      = ld4_nt(aBase + BK);        // tile 1 (staged at iter 0)
    aR[0]      = ld4_nt(aBase + 2 * BK);    // tile 2 (staged at iter 1)
    #pragma unroll
    for (int ks = 0; ks < 2; ++ks) {
        bR[0][0][ks] = *(const s16x8_t*)(bBase0 + 32 * ks);
        bR[0][1][ks] = *(const s16x8_t*)(bBase1 + 32 * ks);
    }
    {
        s16x4_t pk;
        pk[0] = (short)f2bf(a0.x); pk[1] = (short)f2bf(a0.y);
        pk[2] = (short)f2bf(a0.z); pk[3] = (short)f2bf(a0.w);
        *(s16x4_t*)&Asm[0][woff] = pk;
    }
    __syncthreads();   // one-time full drain in prologue is fine

    // ---- main loop: one raw barrier per K-step, no vmcnt drain ----
    #pragma unroll 2
    for (int it = 0; it < K_ITERS; ++it) {
        const int cur = it & 1;
        const int nxt = cur ^ 1;

        // stage tile it+1 into LDS[nxt] (aR[nxt] issued at iter it-2;
        // compiler inserts a counted vmcnt before the converts)
        {
            s16x4_t pk;
            pk[0] = (short)f2bf(aR[nxt].x); pk[1] = (short)f2bf(aR[nxt].y);
            pk[2] = (short)f2bf(aR[nxt].z); pk[3] = (short)f2bf(aR[nxt].w);
            *(s16x4_t*)&Asm[nxt][woff] = pk;
        }

        // A fragments of tile it (both g) from LDS[cur]
        s16x8_t af[2][2];   // [g][ks]
        #pragma unroll
        for (int g = 0; g < 2; ++g)
            #pragma unroll
            for (int ks = 0; ks < 2; ++ks) {
                const int slot = ((g * 2 + ks) * 4 + fq) * 16
                               + ((fl ^ (4 * ks + fq)) & 15);
                af[g][ks] = *(const s16x8_t*)&Asm[cur][slot * 8];
            }

        // prefetch: A tile it+3 (2 deep), B tile it+1 (1 deep)
        const int ta = (it + 3 < K_ITERS) ? (it + 3) : (K_ITERS - 1);
        const int tb = (it + 1 < K_ITERS) ? (it + 1) : (K_ITERS - 1);
        aR[nxt] = ld4_nt(aBase + (size_t)ta * BK);
        const size_t kb = (size_t)tb * BK;
        #pragma unroll
        for (int ks = 0; ks < 2; ++ks) {
            bR[nxt][0][ks] = *(const s16x8_t*)(bBase0 + kb + 32 * ks);
            bR[nxt][1][ks] = *(const s16x8_t*)(bBase1 + kb + 32 * ks);
        }

        // LDS visibility only: stage-writes landed, af reads complete.
        // Global prefetches above stay in flight across the barrier.
        asm volatile("s_waitcnt lgkmcnt(0)" ::: "memory");
        __builtin_amdgcn_sched_barrier(0);
        __builtin_amdgcn_s_barrier();

        #pragma unroll
        for (int ks = 0; ks < 2; ++ks)
            #pragma unroll
            for (int g = 0; g < 2; ++g)
                #pragma unroll
                for (int nt = 0; nt < 2; ++nt)
                    acc[g][nt] = __builtin_amdgcn_mfma_f32_16x16x32_bf16(
                        af[g][ks], bR[cur][nt][ks], acc[g][nt], 0, 0, 0);
    }

    // epilogue: C/D layout col=lane&15, row=(lane>>4)*4+reg; streamed stores
    #pragma unroll
    for (int g = 0; g < 2; ++g)
        #pragma unroll
        for (int nt = 0; nt < 2; ++nt)
            #pragma unroll
            for (int r = 0; r < 4; ++r) {
                const int row = m0 + 4 * fq + r;
                const int col = g * D_FEAT + 32 * w + 16 * nt + fl;
                __builtin_nontemporal_store(acc[g][nt][r],
                    &out[(size_t)row * (2 * D_FEAT) + col]);
            }
}

extern "C" void kernel_launch(void* const* d_in, const int* in_sizes, int n_in,
                              void* d_out, int out_size, void* d_ws, size_t ws_size,
                              hipStream_t stream) {
    const float* x      = (const float*)d_in[0];
    const float* adj_t  = (const float*)d_in[1];
    const float* adj_t2 = (const float*)d_in[2];
    float* out = (float*)d_out;
    unsigned short* xT = (unsigned short*)d_ws;   // 256*8192 bf16 = 4 MiB
    (void)in_sizes; (void)n_in; (void)out_size; (void)ws_size;

    // 1) transpose+convert x -> xT (bf16, [n][k])
    hipLaunchKernelGGL(xpose_kernel, dim3(N_TOT / 64, D_FEAT / 64), dim3(256), 0, stream, x, xT);
    // 2) fused dual GEMM: 512 m-tiles (BM=16) -> 2 blocks/CU, 16 waves/CU
    hipLaunchKernelGGL(h2gcn_kernel, dim3(N_TOT / BM), dim3(512), 0, stream,
                       adj_t, adj_t2, xT, out);
}